// Round 1
// baseline (10226.811 us; speedup 1.0000x reference)
//
#include <hip/hip_runtime.h>
#include <hip/hip_fp16.h>

#define NN 100000
#define NE 1600000
#define NG 128
#define DIN 20
#define DEMB 300
#define DHID 600
#define DOUT 64

static const float BN_EPS_F = 1e-5f;

__device__ __forceinline__ float to_f32(float v) { return v; }
__device__ __forceinline__ float to_f32(__half v) { return __half2float(v); }
__device__ __forceinline__ void st_from_f32(float* p, float v) { *p = v; }
__device__ __forceinline__ void st_from_f32(__half* p, float v) { *p = __float2half(v); }

// ---------------- CSR build (once per call) ----------------

__global__ void count_edges_kernel(const int* __restrict__ dst, const float* __restrict__ ef,
                                   int* __restrict__ counts, float* __restrict__ esum) {
  int e = blockIdx.x * blockDim.x + threadIdx.x;
  if (e >= NE) return;
  int v = dst[e];
  atomicAdd(&counts[v], 1);
  atomicAdd(&esum[v], ef[e]);
}

__global__ __launch_bounds__(1024) void scan_kernel(const int* __restrict__ counts,
                                                    int* __restrict__ row_ptr,
                                                    int* __restrict__ cursor) {
  __shared__ int part[1024];
  int t = threadIdx.x;
  const int chunk = (NN + 1023) / 1024;
  int b0 = t * chunk, b1 = min(b0 + chunk, NN);
  int s = 0;
  for (int i = b0; i < b1; ++i) s += counts[i];
  part[t] = s;
  __syncthreads();
  for (int off = 1; off < 1024; off <<= 1) {
    int v = (t >= off) ? part[t - off] : 0;
    __syncthreads();
    if (t >= off) part[t] += v;
    __syncthreads();
  }
  int run = (t == 0) ? 0 : part[t - 1];
  for (int i = b0; i < b1; ++i) {
    row_ptr[i] = run;
    cursor[i] = run;
    run += counts[i];
  }
  if (t == 1023) row_ptr[NN] = run;
}

__global__ void scatter_kernel(const int* __restrict__ src, const int* __restrict__ dst,
                               int* __restrict__ cursor, int* __restrict__ csr_src) {
  int e = blockIdx.x * blockDim.x + threadIdx.x;
  if (e >= NE) return;
  int pos = atomicAdd(&cursor[dst[e]], 1);
  csr_src[pos] = src[e];
}

// ---------------- SpMM: agg[v,:] = sum_{neighbors} x[src,:] + esum[v] ----------------
// one wave per dst node; lane covers columns lane, lane+64, ... (d<=320)

__global__ __launch_bounds__(256) void spmm_kernel(const float* __restrict__ x,
                                                   const int* __restrict__ row_ptr,
                                                   const int* __restrict__ csr_src,
                                                   const float* __restrict__ esum,
                                                   float* __restrict__ agg, int d) {
  int wid = (blockIdx.x * blockDim.x + threadIdx.x) >> 6;
  int lane = threadIdx.x & 63;
  if (wid >= NN) return;
  float acc[5] = {0.f, 0.f, 0.f, 0.f, 0.f};
  int beg = row_ptr[wid], end = row_ptr[wid + 1];
  for (int j = beg; j < end; ++j) {
    const float* xr = x + (size_t)csr_src[j] * d;
#pragma unroll
    for (int c = 0; c < 5; ++c) {
      int col = lane + (c << 6);
      if (col < d) acc[c] += xr[col];
    }
  }
  float es = esum[wid];
  float* ar = agg + (size_t)wid * d;
#pragma unroll
  for (int c = 0; c < 5; ++c) {
    int col = lane + (c << 6);
    if (col < d) ar[col] = acc[c] + es;
  }
}

// ---------------- fp32 GEMM: C[M,N] = A[M,K] @ B[K,N] + bias (+ReLU), generic edges ----------------
// 128x128 block tile, BK=8, 256 threads, 8x8 microtile.

template <typename TA, typename TO, bool RELU>
__global__ __launch_bounds__(256) void gemm_kernel(const TA* __restrict__ A,
                                                   const float* __restrict__ B,
                                                   const float* __restrict__ bias,
                                                   TO* __restrict__ C, int M, int N, int K) {
  const int BM = 128, BN = 128, BK = 8;
  __shared__ float As[BK][BM + 4];  // +4 pad: loader writes stride-BM, breaks bank aliasing
  __shared__ float Bs[BK][BN];
  int bm = blockIdx.y * BM;
  int bn = blockIdx.x * BN;
  int t = threadIdx.x;
  int tm = (t >> 4) << 3;
  int tn = (t & 15) << 3;
  float acc[8][8] = {};
  int la_k = t & 7, la_m = t >> 3;    // A tile: 128x8, 4 rows per thread
  int lb_n = t & 127, lb_k = t >> 7;  // B tile: 8x128, 4 ks per thread

  for (int k0 = 0; k0 < K; k0 += BK) {
#pragma unroll
    for (int i = 0; i < 4; ++i) {
      int m = la_m + (i << 5);
      int gm = bm + m, gk = k0 + la_k;
      float v = 0.f;
      if (gm < M && gk < K) v = to_f32(A[(size_t)gm * K + gk]);
      As[la_k][m] = v;
    }
#pragma unroll
    for (int i = 0; i < 4; ++i) {
      int k = lb_k + (i << 1);
      int gk = k0 + k, gn = bn + lb_n;
      float v = 0.f;
      if (gk < K && gn < N) v = B[(size_t)gk * N + gn];
      Bs[k][lb_n] = v;
    }
    __syncthreads();
#pragma unroll
    for (int k = 0; k < BK; ++k) {
      float ra[8], rb[8];
#pragma unroll
      for (int i = 0; i < 8; ++i) ra[i] = As[k][tm + i];
#pragma unroll
      for (int j = 0; j < 8; ++j) rb[j] = Bs[k][tn + j];
#pragma unroll
      for (int i = 0; i < 8; ++i)
#pragma unroll
        for (int j = 0; j < 8; ++j) acc[i][j] = fmaf(ra[i], rb[j], acc[i][j]);
    }
    __syncthreads();
  }

#pragma unroll
  for (int i = 0; i < 8; ++i) {
    int gm = bm + tm + i;
    if (gm >= M) continue;
#pragma unroll
    for (int j = 0; j < 8; ++j) {
      int gn = bn + tn + j;
      if (gn >= N) continue;
      float v = acc[i][j] + bias[gn];
      if (RELU) v = fmaxf(v, 0.f);
      st_from_f32(&C[(size_t)gm * N + gn], v);
    }
  }
}

// ---------------- BatchNorm ----------------

__global__ __launch_bounds__(256) void bn_stats_kernel(const float* __restrict__ h,
                                                       float* __restrict__ stats) {
  int t = threadIdx.x;
  const int rows_per_block = (NN + 511) / 512;
  int r0 = blockIdx.x * rows_per_block;
  int r1 = min(r0 + rows_per_block, NN);
  int c0 = t;        // always < 300
  int c1 = t + 256;  // valid if < 300
  bool has1 = (c1 < DEMB);
  float s0 = 0.f, q0 = 0.f, s1 = 0.f, q1 = 0.f;
  for (int r = r0; r < r1; ++r) {
    const float* row = h + (size_t)r * DEMB;
    float v0 = row[c0];
    s0 += v0; q0 += v0 * v0;
    if (has1) { float v1 = row[c1]; s1 += v1; q1 += v1 * v1; }
  }
  atomicAdd(&stats[c0], s0);
  atomicAdd(&stats[DEMB + c0], q0);
  if (has1) {
    atomicAdd(&stats[c1], s1);
    atomicAdd(&stats[DEMB + c1], q1);
  }
}

__global__ void bn_finalize_kernel(const float* __restrict__ stats, const float* __restrict__ gamma,
                                   const float* __restrict__ beta, float* __restrict__ scale,
                                   float* __restrict__ shift) {
  int c = threadIdx.x;
  if (c >= DEMB) return;
  float mu = stats[c] / (float)NN;
  float var = stats[DEMB + c] / (float)NN - mu * mu;
  var = fmaxf(var, 0.f);
  float sc = gamma[c] * rsqrtf(var + BN_EPS_F);
  scale[c] = sc;
  shift[c] = beta[c] - mu * sc;
}

__global__ void bn_apply_kernel(float* __restrict__ h, const float* __restrict__ scale,
                                const float* __restrict__ shift) {
  const long total4 = (long)NN * DEMB / 4;
  long i4 = (long)blockIdx.x * blockDim.x + threadIdx.x;
  if (i4 >= total4) return;
  int c4 = (int)(i4 % (DEMB / 4)) * 4;  // 300 % 4 == 0, float4 never crosses a row
  float4 v = ((float4*)h)[i4];
  v.x = v.x * scale[c4 + 0] + shift[c4 + 0];
  v.y = v.y * scale[c4 + 1] + shift[c4 + 1];
  v.z = v.z * scale[c4 + 2] + shift[c4 + 2];
  v.w = v.w * scale[c4 + 3] + shift[c4 + 3];
  ((float4*)h)[i4] = v;
}

// ---------------- readout ----------------

__global__ __launch_bounds__(256) void pool_kernel(const float* __restrict__ h,
                                                   const int* __restrict__ gid,
                                                   float* __restrict__ gfeat) {
  int g = blockIdx.x;
  __shared__ int sb[2];
  if (threadIdx.x < 2) {
    int target = g + (int)threadIdx.x;
    int lo = 0, hi = NN;
    while (lo < hi) {
      int m = (lo + hi) >> 1;
      if (gid[m] < target) lo = m + 1; else hi = m;
    }
    sb[threadIdx.x] = lo;
  }
  __syncthreads();
  int r0 = sb[0], r1 = sb[1];
  float inv = 1.0f / fmaxf((float)(r1 - r0), 1.0f);
  for (int c = threadIdx.x; c < DEMB; c += blockDim.x) {
    float s = 0.f;
    for (int r = r0; r < r1; ++r) s += h[(size_t)r * DEMB + c];
    gfeat[g * DEMB + c] = s * inv;
  }
}

__global__ void final_gemm_kernel(const float* __restrict__ gf, const float* __restrict__ wt,
                                  const float* __restrict__ bt, float* __restrict__ out) {
  int g = blockIdx.x, t = threadIdx.x;  // 64 threads
  float acc = bt[t];
  const float* row = gf + g * DEMB;
  for (int k = 0; k < DEMB; ++k) acc = fmaf(row[k], wt[k * DOUT + t], acc);
  out[g * DOUT + t] = acc;
}

// ---------------- launch ----------------

extern "C" void kernel_launch(void* const* d_in, const int* in_sizes, int n_in,
                              void* d_out, int out_size, void* d_ws, size_t ws_size,
                              hipStream_t stream) {
  const float* node_feats = (const float*)d_in[0];
  const float* edge_feats = (const float*)d_in[1];
  const int* src = (const int*)d_in[2];
  const int* dst = (const int*)d_in[3];
  const int* gid = (const int*)d_in[4];
  const float* w1_0 = (const float*)d_in[5];
  const float* b1_0 = (const float*)d_in[6];
  const float* w2_0 = (const float*)d_in[7];
  const float* b2_0 = (const float*)d_in[8];
  const float* gamma_0 = (const float*)d_in[9];
  const float* beta_0 = (const float*)d_in[10];
  const float* w1s = (const float*)d_in[11];
  const float* b1s = (const float*)d_in[12];
  const float* w2s = (const float*)d_in[13];
  const float* b2s = (const float*)d_in[14];
  const float* gammas = (const float*)d_in[15];
  const float* betas = (const float*)d_in[16];
  const float* wt = (const float*)d_in[17];
  const float* bt = (const float*)d_in[18];
  float* out = (float*)d_out;

  char* ws = (char*)d_ws;
  size_t off = 0;
  auto carve = [&](size_t bytes) -> void* {
    void* p = ws + off;
    off += (bytes + 255) & ~(size_t)255;
    return p;
  };
  // row bytes: fp32x300 = 1200B == fp16x600 = 1200B -> two ping-pong buffers
  float* bufQ = (float*)carve((size_t)NN * 1200);
  float* bufP = (float*)carve((size_t)NN * 1200);
  float* esum = (float*)carve((size_t)NN * 4);
  int* counts = (int*)carve((size_t)NN * 4);
  int* row_ptr = (int*)carve((size_t)(NN + 1) * 4);
  int* cursor = (int*)carve((size_t)NN * 4);
  int* csr_src = (int*)carve((size_t)NE * 4);
  float* stats = (float*)carve(2 * DEMB * 4);
  float* scale = (float*)carve(DEMB * 4);
  float* shift = (float*)carve(DEMB * 4);
  float* gfeat = (float*)carve((size_t)NG * DEMB * 4);
  (void)ws_size; (void)in_sizes; (void)n_in; (void)out_size;

  hipMemsetAsync(esum, 0, (size_t)NN * 4, stream);
  hipMemsetAsync(counts, 0, (size_t)NN * 4, stream);

  count_edges_kernel<<<(NE + 255) / 256, 256, 0, stream>>>(dst, edge_feats, counts, esum);
  scan_kernel<<<1, 1024, 0, stream>>>(counts, row_ptr, cursor);
  scatter_kernel<<<(NE + 255) / 256, 256, 0, stream>>>(src, dst, cursor, csr_src);

  const float* x = node_feats;
  int d = DIN;
  for (int l = 0; l < 5; ++l) {
    float* agg = (l % 2 == 0) ? bufQ : bufP;
    __half* h1 = (__half*)((l % 2 == 0) ? bufP : bufQ);
    const float* w1 = (l == 0) ? w1_0 : w1s + (size_t)(l - 1) * DEMB * DHID;
    const float* b1 = (l == 0) ? b1_0 : b1s + (size_t)(l - 1) * DHID;
    const float* w2 = (l == 0) ? w2_0 : w2s + (size_t)(l - 1) * DHID * DEMB;
    const float* b2 = (l == 0) ? b2_0 : b2s + (size_t)(l - 1) * DEMB;
    const float* ga = (l == 0) ? gamma_0 : gammas + (size_t)(l - 1) * DEMB;
    const float* be = (l == 0) ? beta_0 : betas + (size_t)(l - 1) * DEMB;

    spmm_kernel<<<(NN * 64 + 255) / 256, 256, 0, stream>>>(x, row_ptr, csr_src, esum, agg, d);

    {
      dim3 grid((DHID + 127) / 128, (NN + 127) / 128);
      gemm_kernel<float, __half, true><<<grid, 256, 0, stream>>>(agg, w1, b1, h1, NN, DHID, d);
    }
    {
      dim3 grid((DEMB + 127) / 128, (NN + 127) / 128);
      gemm_kernel<__half, float, false><<<grid, 256, 0, stream>>>(h1, w2, b2, agg, NN, DEMB, DHID);
    }

    hipMemsetAsync(stats, 0, 2 * DEMB * 4, stream);
    bn_stats_kernel<<<512, 256, 0, stream>>>(agg, stats);
    bn_finalize_kernel<<<1, 320, 0, stream>>>(stats, ga, be, scale, shift);
    bn_apply_kernel<<<(int)(((long)NN * DEMB / 4 + 255) / 256), 256, 0, stream>>>(agg, scale, shift);

    x = agg;
    d = DEMB;
  }

  pool_kernel<<<NG, 256, 0, stream>>>(x, gid, gfeat);
  final_gemm_kernel<<<NG, 64, 0, stream>>>(gfeat, wt, bt, out);
}

// Round 2
// 3333.286 us; speedup vs baseline: 3.0681x; 3.0681x over previous
//
#include <hip/hip_runtime.h>

#define NN 100000
#define NE 1600000
#define NG 128
#define DIN 20
#define DEMB 300
#define DHID 600
#define DOUT 64
// padded dims (multiples of 32; N-dims multiples of 64)
#define DIN_P 32
#define EMB_P 320
#define HID_P 640

static const float BN_EPS_F = 1e-5f;

typedef _Float16 f16x8 __attribute__((ext_vector_type(8)));
typedef _Float16 f16x4 __attribute__((ext_vector_type(4)));
typedef float f32x4 __attribute__((ext_vector_type(4)));

// async global->LDS, 16B per lane; LDS dst = wave-uniform base + lane*16
__device__ __forceinline__ void gload_lds16(const void* g, const void* l) {
  __builtin_amdgcn_global_load_lds(
      (const __attribute__((address_space(1))) unsigned int*)(unsigned long long)g,
      (__attribute__((address_space(3))) unsigned int*)(unsigned long long)(unsigned int)(unsigned long long)l,
      16, 0, 0);
}

// ---------------- CSR build (once per call) ----------------

__global__ void count_edges_kernel(const int* __restrict__ dst, const float* __restrict__ ef,
                                   int* __restrict__ counts, float* __restrict__ esum) {
  int e = blockIdx.x * blockDim.x + threadIdx.x;
  if (e >= NE) return;
  int v = dst[e];
  atomicAdd(&counts[v], 1);
  atomicAdd(&esum[v], ef[e]);
}

__global__ __launch_bounds__(1024) void scan_kernel(const int* __restrict__ counts,
                                                    int* __restrict__ row_ptr,
                                                    int* __restrict__ cursor) {
  __shared__ int part[1024];
  int t = threadIdx.x;
  const int chunk = (NN + 1023) / 1024;
  int b0 = t * chunk, b1 = min(b0 + chunk, NN);
  int s = 0;
  for (int i = b0; i < b1; ++i) s += counts[i];
  part[t] = s;
  __syncthreads();
  for (int off = 1; off < 1024; off <<= 1) {
    int v = (t >= off) ? part[t - off] : 0;
    __syncthreads();
    if (t >= off) part[t] += v;
    __syncthreads();
  }
  int run = (t == 0) ? 0 : part[t - 1];
  for (int i = b0; i < b1; ++i) {
    row_ptr[i] = run;
    cursor[i] = run;
    run += counts[i];
  }
  if (t == 1023) row_ptr[NN] = run;
}

__global__ void scatter_kernel(const int* __restrict__ src, const int* __restrict__ dst,
                               int* __restrict__ cursor, int* __restrict__ csr_src) {
  int e = blockIdx.x * blockDim.x + threadIdx.x;
  if (e >= NE) return;
  int pos = atomicAdd(&cursor[dst[e]], 1);
  csr_src[pos] = src[e];
}

// ---------------- weight repack: w[K][Nsrc] fp32 -> wt[Np][Kp] fp16 (transposed, zero-pad) ----

__global__ void repack_wt_kernel(const float* __restrict__ w, _Float16* __restrict__ out,
                                 int K, int Nsrc, int Np, int Kp) {
  int idx = blockIdx.x * blockDim.x + threadIdx.x;
  if (idx >= Np * Kp) return;
  int n = idx / Kp, k = idx - n * Kp;
  float v = (n < Nsrc && k < K) ? w[(size_t)k * Nsrc + n] : 0.f;
  out[idx] = (_Float16)v;
}

__global__ void pad_bias_kernel(const float* __restrict__ b, float* __restrict__ out, int n, int np) {
  int i = blockIdx.x * blockDim.x + threadIdx.x;
  if (i >= np) return;
  out[i] = (i < n) ? b[i] : 0.f;
}

// ---------------- layer-0 spmm: fp32 x[N][20] -> fp16 agg0[N][32] ----------------

__global__ __launch_bounds__(256) void spmm0_kernel(const float* __restrict__ x,
                                                    const int* __restrict__ row_ptr,
                                                    const int* __restrict__ csr_src,
                                                    const float* __restrict__ esum,
                                                    _Float16* __restrict__ out) {
  int wid = (blockIdx.x * blockDim.x + threadIdx.x) >> 6;
  int lane = threadIdx.x & 63;
  if (wid >= NN) return;
  int beg = row_ptr[wid], end = row_ptr[wid + 1];
  float acc = 0.f;
  int j = beg;
  for (; j + 1 < end; j += 2) {
    int s0 = csr_src[j], s1 = csr_src[j + 1];
    if (lane < DIN) {
      acc += x[(size_t)s0 * DIN + lane];
      acc += x[(size_t)s1 * DIN + lane];
    }
  }
  if (j < end) {
    int s0 = csr_src[j];
    if (lane < DIN) acc += x[(size_t)s0 * DIN + lane];
  }
  if (lane < DIN_P) {
    float v = (lane < DIN) ? acc + esum[wid] : 0.f;
    out[(size_t)wid * DIN_P + lane] = (_Float16)v;
  }
}

// ---------------- fused spmm (layers 1..4): gather raw h2 fp16, apply prev BN on the fly ----
// out[v,c] = scale[c]*sum_{u in N(v)} h2[u,c] + deg(v)*shift[c] + esum[v]

__global__ __launch_bounds__(256) void spmm_f16_kernel(const _Float16* __restrict__ x,
                                                       const float* __restrict__ scale,
                                                       const float* __restrict__ shift,
                                                       const int* __restrict__ row_ptr,
                                                       const int* __restrict__ csr_src,
                                                       const float* __restrict__ esum,
                                                       _Float16* __restrict__ out) {
  int wid = (blockIdx.x * blockDim.x + threadIdx.x) >> 6;
  int lane = threadIdx.x & 63;
  if (wid >= NN) return;
  int beg = row_ptr[wid], end = row_ptr[wid + 1];
  const bool two = lane < 16;  // 80 8B-chunks per row: chunk lane for all, chunk 64+lane for lane<16
  const int q0 = lane, q1 = 64 + lane;
  float a0 = 0.f, a1 = 0.f, a2 = 0.f, a3 = 0.f;
  float b0 = 0.f, b1 = 0.f, b2 = 0.f, b3 = 0.f;
  const f16x4* xb = (const f16x4*)x;
  int j = beg;
  for (; j + 3 < end; j += 4) {
    int s0 = csr_src[j], s1 = csr_src[j + 1], s2 = csr_src[j + 2], s3 = csr_src[j + 3];
    const f16x4* r0 = xb + (size_t)s0 * 80;
    const f16x4* r1 = xb + (size_t)s1 * 80;
    const f16x4* r2 = xb + (size_t)s2 * 80;
    const f16x4* r3 = xb + (size_t)s3 * 80;
    f16x4 v0 = r0[q0], v1 = r1[q0], v2 = r2[q0], v3 = r3[q0];
    f16x4 w0 = {}, w1 = {}, w2 = {}, w3 = {};
    if (two) { w0 = r0[q1]; w1 = r1[q1]; w2 = r2[q1]; w3 = r3[q1]; }
    a0 += (float)v0[0] + (float)v1[0] + (float)v2[0] + (float)v3[0];
    a1 += (float)v0[1] + (float)v1[1] + (float)v2[1] + (float)v3[1];
    a2 += (float)v0[2] + (float)v1[2] + (float)v2[2] + (float)v3[2];
    a3 += (float)v0[3] + (float)v1[3] + (float)v2[3] + (float)v3[3];
    if (two) {
      b0 += (float)w0[0] + (float)w1[0] + (float)w2[0] + (float)w3[0];
      b1 += (float)w0[1] + (float)w1[1] + (float)w2[1] + (float)w3[1];
      b2 += (float)w0[2] + (float)w1[2] + (float)w2[2] + (float)w3[2];
      b3 += (float)w0[3] + (float)w1[3] + (float)w2[3] + (float)w3[3];
    }
  }
  for (; j < end; ++j) {
    const f16x4* r0 = xb + (size_t)csr_src[j] * 80;
    f16x4 v0 = r0[q0];
    a0 += (float)v0[0]; a1 += (float)v0[1]; a2 += (float)v0[2]; a3 += (float)v0[3];
    if (two) {
      f16x4 w0 = r0[q1];
      b0 += (float)w0[0]; b1 += (float)w0[1]; b2 += (float)w0[2]; b3 += (float)w0[3];
    }
  }
  float deg = (float)(end - beg);
  float es = esum[wid];
  int c0 = lane * 4;
  f16x4 o;
  o[0] = (_Float16)(a0 * scale[c0 + 0] + deg * shift[c0 + 0] + es);
  o[1] = (_Float16)(a1 * scale[c0 + 1] + deg * shift[c0 + 1] + es);
  o[2] = (_Float16)(a2 * scale[c0 + 2] + deg * shift[c0 + 2] + es);
  o[3] = (_Float16)(a3 * scale[c0 + 3] + deg * shift[c0 + 3] + es);
  ((f16x4*)out)[(size_t)wid * 80 + q0] = o;
  if (two) {
    int c1 = 256 + lane * 4;
    f16x4 p;
    p[0] = (_Float16)(b0 * scale[c1 + 0] + deg * shift[c1 + 0] + es);
    p[1] = (_Float16)(b1 * scale[c1 + 1] + deg * shift[c1 + 1] + es);
    p[2] = (_Float16)(b2 * scale[c1 + 2] + deg * shift[c1 + 2] + es);
    p[3] = (_Float16)(b3 * scale[c1 + 3] + deg * shift[c1 + 3] + es);
    ((f16x4*)out)[(size_t)wid * 80 + q1] = p;
  }
}

// ---------------- MFMA GEMM: C[M][N] = A[M][K] @ Bt[N][K]^T + bias, fp16 in/out, fp32 acc ----
// BM=128, BN=64, BK=32; 128 threads = 2 waves; wave tile 64x64 as 4x4 frags of 16x16x32.
// A and B staged into LDS in exact MFMA fragment order via global_load_lds (16B/lane).

template <bool RELU>
__global__ __launch_bounds__(128) void mfma_gemm_kernel(const _Float16* __restrict__ A,
                                                        const _Float16* __restrict__ Bt,
                                                        const float* __restrict__ bias,
                                                        _Float16* __restrict__ C,
                                                        int M, int N, int K) {
  __shared__ _Float16 lds[12 * 512];  // 8 A-chunks + 4 B-chunks, 1KB each
  const int t = threadIdx.x;
  const int wv = t >> 6;
  const int lane = t & 63;
  const int fm = lane & 15;
  const int k8 = (lane >> 4) * 8;  // fragment k-offset: 8 contiguous halves
  const int m0 = blockIdx.y * 128;
  const int n0 = blockIdx.x * 64;

  f32x4 acc[4][4] = {};

  float bi[4];
#pragma unroll
  for (int ni = 0; ni < 4; ++ni) bi[ni] = bias[n0 + ni * 16 + fm];

  for (int k0 = 0; k0 < K; k0 += 32) {
    // stage this wave's 4 A fragment-chunks (rows m0 + (4*wv+i)*16 + fm)
#pragma unroll
    for (int i = 0; i < 4; ++i) {
      int mi = 4 * wv + i;
      int m = m0 + mi * 16 + fm;
      m = min(m, M - 1);
      gload_lds16(A + (size_t)m * K + (k0 + k8), &lds[mi * 512 + lane * 8]);
    }
    // stage 2 of the 4 B fragment-chunks (cols n0 + ni*16 + fm)
#pragma unroll
    for (int i = 0; i < 2; ++i) {
      int ni = 2 * wv + i;
      int n = n0 + ni * 16 + fm;
      gload_lds16(Bt + (size_t)n * K + (k0 + k8), &lds[(8 + ni) * 512 + lane * 8]);
    }
    __syncthreads();
    f16x8 a[4], b[4];
#pragma unroll
    for (int i = 0; i < 4; ++i) a[i] = *(const f16x8*)&lds[(4 * wv + i) * 512 + lane * 8];
#pragma unroll
    for (int i = 0; i < 4; ++i) b[i] = *(const f16x8*)&lds[(8 + i) * 512 + lane * 8];
#pragma unroll
    for (int mi = 0; mi < 4; ++mi)
#pragma unroll
      for (int ni = 0; ni < 4; ++ni)
        acc[mi][ni] = __builtin_amdgcn_mfma_f32_16x16x32_f16(a[mi], b[ni], acc[mi][ni], 0, 0, 0);
    __syncthreads();
  }

  // epilogue: C/D layout col=lane&15, row=(lane>>4)*4+reg
  const int row_q = (lane >> 4) * 4;
#pragma unroll
  for (int mi = 0; mi < 4; ++mi) {
    int rbase = m0 + wv * 64 + mi * 16 + row_q;
#pragma unroll
    for (int ni = 0; ni < 4; ++ni) {
      int col = n0 + ni * 16 + fm;
#pragma unroll
      for (int r = 0; r < 4; ++r) {
        int row = rbase + r;
        if (row < M) {
          float v = acc[mi][ni][r] + bi[ni];
          if (RELU) v = fmaxf(v, 0.f);
          C[(size_t)row * N + col] = (_Float16)v;
        }
      }
    }
  }
}

// ---------------- BatchNorm stats over raw h2 fp16 [N][EMB_P], cols < 300 ----------------

__global__ __launch_bounds__(320) void bn_stats_kernel(const _Float16* __restrict__ h,
                                                       float* __restrict__ stats) {
  int c = threadIdx.x;  // 0..319
  const int rpb = (NN + 511) / 512;
  int r0 = blockIdx.x * rpb, r1 = min(r0 + rpb, NN);
  if (c >= DEMB) return;
  float s = 0.f, q = 0.f;
  for (int r = r0; r < r1; ++r) {
    float v = (float)h[(size_t)r * EMB_P + c];
    s += v;
    q += v * v;
  }
  atomicAdd(&stats[c], s);
  atomicAdd(&stats[EMB_P + c], q);
}

__global__ void bn_finalize_kernel(const float* __restrict__ stats, const float* __restrict__ gamma,
                                   const float* __restrict__ beta, float* __restrict__ scale,
                                   float* __restrict__ shift) {
  int c = threadIdx.x;
  if (c >= EMB_P) return;
  if (c < DEMB) {
    float mu = stats[c] / (float)NN;
    float var = fmaxf(stats[EMB_P + c] / (float)NN - mu * mu, 0.f);
    float sc = gamma[c] * rsqrtf(var + BN_EPS_F);
    scale[c] = sc;
    shift[c] = beta[c] - mu * sc;
  } else {
    scale[c] = 0.f;
    shift[c] = 0.f;
  }
}

// ---------------- readout: avg-pool (+ last BN applied on the fly) then Linear ----------------

__global__ __launch_bounds__(256) void pool_kernel(const _Float16* __restrict__ h,
                                                   const float* __restrict__ scale,
                                                   const float* __restrict__ shift,
                                                   const int* __restrict__ gid,
                                                   float* __restrict__ gfeat) {
  int g = blockIdx.x;
  __shared__ int sb[2];
  if (threadIdx.x < 2) {
    int target = g + (int)threadIdx.x;
    int lo = 0, hi = NN;
    while (lo < hi) {
      int m = (lo + hi) >> 1;
      if (gid[m] < target) lo = m + 1; else hi = m;
    }
    sb[threadIdx.x] = lo;
  }
  __syncthreads();
  int r0 = sb[0], r1 = sb[1];
  int cnt = r1 - r0;
  float inv = cnt > 0 ? 1.0f / (float)cnt : 0.f;
  for (int c = threadIdx.x; c < DEMB; c += blockDim.x) {
    float s = 0.f;
    for (int r = r0; r < r1; ++r) s += (float)h[(size_t)r * EMB_P + c];
    gfeat[g * DEMB + c] = (cnt > 0) ? (s * inv) * scale[c] + shift[c] : 0.f;
  }
}

__global__ void final_gemm_kernel(const float* __restrict__ gf, const float* __restrict__ wt,
                                  const float* __restrict__ bt, float* __restrict__ out) {
  int g = blockIdx.x, t = threadIdx.x;  // 64 threads
  float acc = bt[t];
  const float* row = gf + g * DEMB;
  for (int k = 0; k < DEMB; ++k) acc = fmaf(row[k], wt[k * DOUT + t], acc);
  out[g * DOUT + t] = acc;
}

// ---------------- launch ----------------

extern "C" void kernel_launch(void* const* d_in, const int* in_sizes, int n_in,
                              void* d_out, int out_size, void* d_ws, size_t ws_size,
                              hipStream_t stream) {
  const float* node_feats = (const float*)d_in[0];
  const float* edge_feats = (const float*)d_in[1];
  const int* src = (const int*)d_in[2];
  const int* dst = (const int*)d_in[3];
  const int* gid = (const int*)d_in[4];
  const float* w1_0 = (const float*)d_in[5];
  const float* b1_0 = (const float*)d_in[6];
  const float* w2_0 = (const float*)d_in[7];
  const float* b2_0 = (const float*)d_in[8];
  const float* gamma_0 = (const float*)d_in[9];
  const float* beta_0 = (const float*)d_in[10];
  const float* w1s = (const float*)d_in[11];
  const float* b1s = (const float*)d_in[12];
  const float* w2s = (const float*)d_in[13];
  const float* b2s = (const float*)d_in[14];
  const float* gammas = (const float*)d_in[15];
  const float* betas = (const float*)d_in[16];
  const float* wt = (const float*)d_in[17];
  const float* bt = (const float*)d_in[18];
  float* out = (float*)d_out;
  (void)in_sizes; (void)n_in; (void)out_size; (void)ws_size;

  char* ws = (char*)d_ws;
  size_t off = 0;
  auto carve = [&](size_t bytes) -> void* {
    void* p = ws + off;
    off += (bytes + 255) & ~(size_t)255;
    return p;
  };
  _Float16* P0 = (_Float16*)carve((size_t)NN * EMB_P * 2);   // agg (also holds [N][32] for l0)
  _Float16* P1 = (_Float16*)carve((size_t)NN * EMB_P * 2);   // raw h2 (pre-BN)
  _Float16* Q  = (_Float16*)carve((size_t)NN * HID_P * 2);   // h1
  float* esum   = (float*)carve((size_t)NN * 4);
  int* counts   = (int*)carve((size_t)NN * 4);
  int* row_ptr  = (int*)carve((size_t)(NN + 1) * 4);
  int* cursor   = (int*)carve((size_t)NN * 4);
  int* csr_src  = (int*)carve((size_t)NE * 4);
  _Float16* w1t0 = (_Float16*)carve((size_t)HID_P * DIN_P * 2);
  _Float16* w1t  = (_Float16*)carve((size_t)4 * HID_P * EMB_P * 2);
  _Float16* w2t  = (_Float16*)carve((size_t)5 * EMB_P * HID_P * 2);
  float* b1p   = (float*)carve((size_t)5 * HID_P * 4);
  float* b2p   = (float*)carve((size_t)5 * EMB_P * 4);
  float* stats = (float*)carve(2 * EMB_P * 4);
  float* scale = (float*)carve(EMB_P * 4);
  float* shift = (float*)carve(EMB_P * 4);
  float* gfeat = (float*)carve((size_t)NG * DEMB * 4);

  hipMemsetAsync(esum, 0, (size_t)NN * 4, stream);
  hipMemsetAsync(counts, 0, (size_t)NN * 4, stream);

  // CSR by dst + per-node edge-feature sums
  count_edges_kernel<<<(NE + 255) / 256, 256, 0, stream>>>(dst, edge_feats, counts, esum);
  scan_kernel<<<1, 1024, 0, stream>>>(counts, row_ptr, cursor);
  scatter_kernel<<<(NE + 255) / 256, 256, 0, stream>>>(src, dst, cursor, csr_src);

  // weight repacks (fp16, transposed [N][K], zero-padded)
  repack_wt_kernel<<<(HID_P * DIN_P + 255) / 256, 256, 0, stream>>>(w1_0, w1t0, DIN, DHID, HID_P, DIN_P);
  for (int l = 0; l < 4; ++l) {
    repack_wt_kernel<<<(HID_P * EMB_P + 255) / 256, 256, 0, stream>>>(
        w1s + (size_t)l * DEMB * DHID, w1t + (size_t)l * HID_P * EMB_P, DEMB, DHID, HID_P, EMB_P);
  }
  repack_wt_kernel<<<(EMB_P * HID_P + 255) / 256, 256, 0, stream>>>(w2_0, w2t, DHID, DEMB, EMB_P, HID_P);
  for (int l = 0; l < 4; ++l) {
    repack_wt_kernel<<<(EMB_P * HID_P + 255) / 256, 256, 0, stream>>>(
        w2s + (size_t)l * DHID * DEMB, w2t + (size_t)(l + 1) * EMB_P * HID_P, DHID, DEMB, EMB_P, HID_P);
  }
  pad_bias_kernel<<<(HID_P + 255) / 256, 256, 0, stream>>>(b1_0, b1p, DHID, HID_P);
  pad_bias_kernel<<<(EMB_P + 255) / 256, 256, 0, stream>>>(b2_0, b2p, DEMB, EMB_P);
  for (int l = 0; l < 4; ++l) {
    pad_bias_kernel<<<(HID_P + 255) / 256, 256, 0, stream>>>(b1s + (size_t)l * DHID, b1p + (size_t)(l + 1) * HID_P, DHID, HID_P);
    pad_bias_kernel<<<(EMB_P + 255) / 256, 256, 0, stream>>>(b2s + (size_t)l * DEMB, b2p + (size_t)(l + 1) * EMB_P, DEMB, EMB_P);
  }

  const int MT = (NN + 127) / 128;  // 782 M-tiles
  const int spmm_blocks = (NN * 64 + 255) / 256;

  for (int l = 0; l < 5; ++l) {
    const _Float16* w1t_l = (l == 0) ? w1t0 : w1t + (size_t)(l - 1) * HID_P * EMB_P;
    const _Float16* w2t_l = w2t + (size_t)l * EMB_P * HID_P;
    const float* b1p_l = b1p + (size_t)l * HID_P;
    const float* b2p_l = b2p + (size_t)l * EMB_P;
    const float* ga = (l == 0) ? gamma_0 : gammas + (size_t)(l - 1) * DEMB;
    const float* be = (l == 0) ? beta_0 : betas + (size_t)(l - 1) * DEMB;
    int K1 = (l == 0) ? DIN_P : EMB_P;

    if (l == 0) {
      spmm0_kernel<<<spmm_blocks, 256, 0, stream>>>(node_feats, row_ptr, csr_src, esum, P0);
    } else {
      // gather raw h2 of previous layer, apply prev BN (scale/shift) fused
      spmm_f16_kernel<<<spmm_blocks, 256, 0, stream>>>(P1, scale, shift, row_ptr, csr_src, esum, P0);
    }

    mfma_gemm_kernel<true><<<dim3(HID_P / 64, MT), 128, 0, stream>>>(P0, w1t_l, b1p_l, Q, NN, HID_P, K1);
    mfma_gemm_kernel<false><<<dim3(EMB_P / 64, MT), 128, 0, stream>>>(Q, w2t_l, b2p_l, P1, NN, EMB_P, HID_P);

    hipMemsetAsync(stats, 0, 2 * EMB_P * 4, stream);
    bn_stats_kernel<<<512, 320, 0, stream>>>(P1, stats);
    bn_finalize_kernel<<<1, EMB_P, 0, stream>>>(stats, ga, be, scale, shift);
  }

  pool_kernel<<<NG, 256, 0, stream>>>(P1, scale, shift, gid, gfeat);
  final_gemm_kernel<<<NG, 64, 0, stream>>>(gfeat, wt, bt, out);
}

// Round 3
// 3067.041 us; speedup vs baseline: 3.3344x; 1.0868x over previous
//
#include <hip/hip_runtime.h>

#define NN 100000
#define NE 1600000
#define NG 128
#define DIN 20
#define DEMB 300
#define DHID 600
#define DOUT 64
// padded dims
#define DIN_P 32
#define EMB_P 320   // activation storage width (multiple of 32)
#define HID_P 640
#define EMB_G 384   // gemm2 N-dim padding (multiple of 128)

static const float BN_EPS_F = 1e-5f;

typedef _Float16 f16x8 __attribute__((ext_vector_type(8)));
typedef float f32x4 __attribute__((ext_vector_type(4)));

// ---------------- CSR build (once per call) ----------------

__global__ void count_edges_kernel(const int* __restrict__ dst, const float* __restrict__ ef,
                                   int* __restrict__ counts, float* __restrict__ esum) {
  int e = blockIdx.x * blockDim.x + threadIdx.x;
  if (e >= NE) return;
  int v = dst[e];
  atomicAdd(&counts[v], 1);
  atomicAdd(&esum[v], ef[e]);
}

__global__ __launch_bounds__(1024) void scan_kernel(const int* __restrict__ counts,
                                                    int* __restrict__ row_ptr,
                                                    int* __restrict__ cursor) {
  __shared__ int part[1024];
  int t = threadIdx.x;
  const int chunk = (NN + 1023) / 1024;
  int b0 = t * chunk, b1 = min(b0 + chunk, NN);
  int s = 0;
  for (int i = b0; i < b1; ++i) s += counts[i];
  part[t] = s;
  __syncthreads();
  for (int off = 1; off < 1024; off <<= 1) {
    int v = (t >= off) ? part[t - off] : 0;
    __syncthreads();
    if (t >= off) part[t] += v;
    __syncthreads();
  }
  int run = (t == 0) ? 0 : part[t - 1];
  for (int i = b0; i < b1; ++i) {
    row_ptr[i] = run;
    cursor[i] = run;
    run += counts[i];
  }
  if (t == 1023) row_ptr[NN] = run;
}

__global__ void scatter_kernel(const int* __restrict__ src, const int* __restrict__ dst,
                               int* __restrict__ cursor, int* __restrict__ csr_src) {
  int e = blockIdx.x * blockDim.x + threadIdx.x;
  if (e >= NE) return;
  int pos = atomicAdd(&cursor[dst[e]], 1);
  csr_src[pos] = src[e];
}

// ---------------- weight repack: w[K][Nsrc] fp32 -> wt[Np][Kp] fp16 (transposed, zero-pad) ----

__global__ void repack_wt_kernel(const float* __restrict__ w, _Float16* __restrict__ out,
                                 int K, int Nsrc, int Np, int Kp) {
  int idx = blockIdx.x * blockDim.x + threadIdx.x;
  if (idx >= Np * Kp) return;
  int n = idx / Kp, k = idx - n * Kp;
  float v = (n < Nsrc && k < K) ? w[(size_t)k * Nsrc + n] : 0.f;
  out[idx] = (_Float16)v;
}

__global__ void pad_bias_kernel(const float* __restrict__ b, float* __restrict__ out, int n, int np) {
  int i = blockIdx.x * blockDim.x + threadIdx.x;
  if (i >= np) return;
  out[i] = (i < n) ? b[i] : 0.f;
}

// ---------------- layer-0 spmm: fp32 x[N][20] -> fp16 agg0[N][32] ----------------

__global__ __launch_bounds__(256) void spmm0_kernel(const float* __restrict__ x,
                                                    const int* __restrict__ row_ptr,
                                                    const int* __restrict__ csr_src,
                                                    const float* __restrict__ esum,
                                                    _Float16* __restrict__ out) {
  int wid = (blockIdx.x * blockDim.x + threadIdx.x) >> 6;
  int lane = threadIdx.x & 63;
  if (wid >= NN) return;
  int beg = row_ptr[wid], end = row_ptr[wid + 1];
  float acc = 0.f;
  int j = beg;
  for (; j + 1 < end; j += 2) {
    int s0 = csr_src[j], s1 = csr_src[j + 1];
    if (lane < DIN) {
      acc += x[(size_t)s0 * DIN + lane];
      acc += x[(size_t)s1 * DIN + lane];
    }
  }
  if (j < end) {
    int s0 = csr_src[j];
    if (lane < DIN) acc += x[(size_t)s0 * DIN + lane];
  }
  if (lane < DIN_P) {
    float v = (lane < DIN) ? acc + esum[wid] : 0.f;
    out[(size_t)wid * DIN_P + lane] = (_Float16)v;
  }
}

// ---------------- fused spmm (layers 1..4): gather raw h2 fp16, apply prev BN on the fly ----
// out[v,c] = scale[c]*sum_{u in N(v)} h2[u,c] + deg(v)*shift[c] + esum[v]
// wave per node; lanes 0..39 each own one f16x8 column-octet; 8-neighbor unroll.

__global__ __launch_bounds__(256) void spmm_f16_kernel(const _Float16* __restrict__ x,
                                                       const float* __restrict__ scale,
                                                       const float* __restrict__ shift,
                                                       const int* __restrict__ row_ptr,
                                                       const int* __restrict__ csr_src,
                                                       const float* __restrict__ esum,
                                                       _Float16* __restrict__ out) {
  int wid = (blockIdx.x * blockDim.x + threadIdx.x) >> 6;
  int lane = threadIdx.x & 63;
  if (wid >= NN) return;
  int beg = row_ptr[wid], end = row_ptr[wid + 1];
  float deg = (float)(end - beg);
  float es = esum[wid];
  if (lane >= 40) return;
  const f16x8* xb = (const f16x8*)x;
  float acc[8] = {};
  int j = beg;
  for (; j + 7 < end; j += 8) {
    int s0 = csr_src[j + 0], s1 = csr_src[j + 1], s2 = csr_src[j + 2], s3 = csr_src[j + 3];
    int s4 = csr_src[j + 4], s5 = csr_src[j + 5], s6 = csr_src[j + 6], s7 = csr_src[j + 7];
    f16x8 v0 = xb[(size_t)s0 * 40 + lane];
    f16x8 v1 = xb[(size_t)s1 * 40 + lane];
    f16x8 v2 = xb[(size_t)s2 * 40 + lane];
    f16x8 v3 = xb[(size_t)s3 * 40 + lane];
    f16x8 v4 = xb[(size_t)s4 * 40 + lane];
    f16x8 v5 = xb[(size_t)s5 * 40 + lane];
    f16x8 v6 = xb[(size_t)s6 * 40 + lane];
    f16x8 v7 = xb[(size_t)s7 * 40 + lane];
#pragma unroll
    for (int i = 0; i < 8; ++i) {
      acc[i] += ((float)v0[i] + (float)v1[i]) + ((float)v2[i] + (float)v3[i]) +
                ((float)v4[i] + (float)v5[i]) + ((float)v6[i] + (float)v7[i]);
    }
  }
  for (; j < end; ++j) {
    f16x8 v0 = xb[(size_t)csr_src[j] * 40 + lane];
#pragma unroll
    for (int i = 0; i < 8; ++i) acc[i] += (float)v0[i];
  }
  int c = lane * 8;
  f16x8 o;
#pragma unroll
  for (int i = 0; i < 8; ++i)
    o[i] = (_Float16)(acc[i] * scale[c + i] + deg * shift[c + i] + es);
  ((f16x8*)(out))[(size_t)wid * 40 + lane] = o;
}

// ---------------- register-streaming MFMA GEMM: C[M][ldC] = A[M][K] @ Bt[Npad][K]^T + bias ----
// 256 threads = 4 waves in 2x2; wave tile 64x64 = 4x4 frags of 16x16x32 f16.
// Fragments loaded straight global->VGPR (16B/lane, contiguous), prefetched one K-step ahead.
// No LDS, no barriers in the K-loop. Optional fused BN-stats reduction in the epilogue.

template <bool RELU, bool STATS>
__global__ __launch_bounds__(256) void gemm_rs_kernel(const _Float16* __restrict__ A,
                                                      const _Float16* __restrict__ Bt,
                                                      const float* __restrict__ bias,
                                                      _Float16* __restrict__ C,
                                                      int M, int K, int ldC, int NREAL,
                                                      float* __restrict__ stats) {
  const int t = threadIdx.x;
  const int wv = t >> 6;
  const int lane = t & 63;
  const int fm = lane & 15;
  const int k8 = (lane >> 4) * 8;
  const int m0 = blockIdx.y * 128 + (wv >> 1) * 64;
  const int n0 = blockIdx.x * 128 + (wv & 1) * 64;

  const _Float16* Ap[4];
  const _Float16* Bp[4];
#pragma unroll
  for (int i = 0; i < 4; ++i) {
    int r = m0 + i * 16 + fm;
    r = min(r, M - 1);
    Ap[i] = A + (size_t)r * K + k8;
  }
#pragma unroll
  for (int i = 0; i < 4; ++i) Bp[i] = Bt + (size_t)(n0 + i * 16 + fm) * K + k8;

  f32x4 acc[4][4] = {};
  f16x8 a[4], b[4];
#pragma unroll
  for (int i = 0; i < 4; ++i) a[i] = *(const f16x8*)Ap[i];
#pragma unroll
  for (int i = 0; i < 4; ++i) b[i] = *(const f16x8*)Bp[i];

  for (int k0 = 32; k0 <= K; k0 += 32) {
    f16x8 an[4], bn[4];
    if (k0 < K) {
#pragma unroll
      for (int i = 0; i < 4; ++i) an[i] = *(const f16x8*)(Ap[i] + k0);
#pragma unroll
      for (int i = 0; i < 4; ++i) bn[i] = *(const f16x8*)(Bp[i] + k0);
    }
#pragma unroll
    for (int mi = 0; mi < 4; ++mi)
#pragma unroll
      for (int ni = 0; ni < 4; ++ni)
        acc[mi][ni] = __builtin_amdgcn_mfma_f32_16x16x32_f16(a[mi], b[ni], acc[mi][ni], 0, 0, 0);
    if (k0 < K) {
#pragma unroll
      for (int i = 0; i < 4; ++i) { a[i] = an[i]; b[i] = bn[i]; }
    }
  }

  // epilogue: C/D layout col=lane&15, row=(lane>>4)*4+reg
  float bi[4];
#pragma unroll
  for (int ni = 0; ni < 4; ++ni) bi[ni] = bias[n0 + ni * 16 + fm];
  const int rq = (lane >> 4) * 4;
  float ssum[4] = {}, ssq[4] = {};
#pragma unroll
  for (int mi = 0; mi < 4; ++mi) {
#pragma unroll
    for (int ni = 0; ni < 4; ++ni) {
      int col = n0 + ni * 16 + fm;
#pragma unroll
      for (int r = 0; r < 4; ++r) {
        int row = m0 + mi * 16 + rq + r;
        float v = acc[mi][ni][r] + bi[ni];
        if (RELU) v = fmaxf(v, 0.f);
        if (row < M && col < NREAL) C[(size_t)row * ldC + col] = (_Float16)v;
        if (STATS && row < M) { ssum[ni] += v; ssq[ni] += v * v; }
      }
    }
  }
  if (STATS) {
    __shared__ float sred[2][128];
    if (t < 128) { sred[0][t] = 0.f; sred[1][t] = 0.f; }
    __syncthreads();
    const int wn = (wv & 1) * 64;
#pragma unroll
    for (int ni = 0; ni < 4; ++ni) {
      atomicAdd(&sred[0][wn + ni * 16 + fm], ssum[ni]);
      atomicAdd(&sred[1][wn + ni * 16 + fm], ssq[ni]);
    }
    __syncthreads();
    if (t < 128) {
      int gc = blockIdx.x * 128 + t;
      atomicAdd(&stats[gc], sred[0][t]);
      atomicAdd(&stats[EMB_G + gc], sred[1][t]);
    }
  }
}

// ---------------- BN finalize ----------------

__global__ void bn_finalize_kernel(const float* __restrict__ stats, const float* __restrict__ gamma,
                                   const float* __restrict__ beta, float* __restrict__ scale,
                                   float* __restrict__ shift) {
  int c = threadIdx.x;
  if (c >= EMB_G) return;
  if (c < DEMB) {
    float mu = stats[c] / (float)NN;
    float var = fmaxf(stats[EMB_G + c] / (float)NN - mu * mu, 0.f);
    float sc = gamma[c] * rsqrtf(var + BN_EPS_F);
    scale[c] = sc;
    shift[c] = beta[c] - mu * sc;
  } else {
    scale[c] = 0.f;
    shift[c] = 0.f;
  }
}

// ---------------- readout ----------------
// pool2: wave per contiguous row chunk, coalesced f16x8 reads, per-graph register acc
// (gid sorted), flush via atomicAdd into graw[G][EMB_P].

#define POOL_BLOCKS 784

__global__ __launch_bounds__(256) void pool2_kernel(const _Float16* __restrict__ h,
                                                    const int* __restrict__ gid,
                                                    float* __restrict__ graw) {
  const int w = (blockIdx.x * 256 + threadIdx.x) >> 6;
  const int lane = threadIdx.x & 63;
  const int NW = POOL_BLOCKS * 4;
  const int rpw = (NN + NW - 1) / NW;
  int r0 = w * rpw, r1 = min(r0 + rpw, NN);
  if (r0 >= r1 || lane >= 40) return;
  const f16x8* hb = (const f16x8*)h;
  float acc[8] = {};
  int curg = gid[r0];
  for (int r = r0; r < r1; ++r) {
    int g = gid[r];
    if (g != curg) {
#pragma unroll
      for (int i = 0; i < 8; ++i) {
        atomicAdd(&graw[curg * EMB_P + lane * 8 + i], acc[i]);
        acc[i] = 0.f;
      }
      curg = g;
    }
    f16x8 v = hb[(size_t)r * 40 + lane];
#pragma unroll
    for (int i = 0; i < 8; ++i) acc[i] += (float)v[i];
  }
#pragma unroll
  for (int i = 0; i < 8; ++i) atomicAdd(&graw[curg * EMB_P + lane * 8 + i], acc[i]);
}

// final: apply count-divide + last BN inline, then 300x64 matvec per graph
__global__ void final_kernel(const float* __restrict__ graw, const int* __restrict__ gid,
                             const float* __restrict__ scale, const float* __restrict__ shift,
                             const float* __restrict__ wt, const float* __restrict__ bt,
                             float* __restrict__ out) {
  int g = blockIdx.x, t = threadIdx.x;  // 64 threads
  __shared__ int sb[2];
  if (t < 2) {
    int target = g + t;
    int lo = 0, hi = NN;
    while (lo < hi) {
      int m = (lo + hi) >> 1;
      if (gid[m] < target) lo = m + 1; else hi = m;
    }
    sb[t] = lo;
  }
  __syncthreads();
  int cnt = sb[1] - sb[0];
  float inv = cnt > 0 ? 1.0f / (float)cnt : 0.f;
  float sh_on = cnt > 0 ? 1.0f : 0.f;
  float acc = bt[t];
  const float* row = graw + g * EMB_P;
  for (int k = 0; k < DEMB; ++k) {
    float gf = row[k] * inv * scale[k] + sh_on * shift[k];
    acc = fmaf(gf, wt[k * DOUT + t], acc);
  }
  out[g * DOUT + t] = acc;
}

// ---------------- launch ----------------

extern "C" void kernel_launch(void* const* d_in, const int* in_sizes, int n_in,
                              void* d_out, int out_size, void* d_ws, size_t ws_size,
                              hipStream_t stream) {
  const float* node_feats = (const float*)d_in[0];
  const float* edge_feats = (const float*)d_in[1];
  const int* src = (const int*)d_in[2];
  const int* dst = (const int*)d_in[3];
  const int* gid = (const int*)d_in[4];
  const float* w1_0 = (const float*)d_in[5];
  const float* b1_0 = (const float*)d_in[6];
  const float* w2_0 = (const float*)d_in[7];
  const float* b2_0 = (const float*)d_in[8];
  const float* gamma_0 = (const float*)d_in[9];
  const float* beta_0 = (const float*)d_in[10];
  const float* w1s = (const float*)d_in[11];
  const float* b1s = (const float*)d_in[12];
  const float* w2s = (const float*)d_in[13];
  const float* b2s = (const float*)d_in[14];
  const float* gammas = (const float*)d_in[15];
  const float* betas = (const float*)d_in[16];
  const float* wt = (const float*)d_in[17];
  const float* bt = (const float*)d_in[18];
  float* out = (float*)d_out;
  (void)in_sizes; (void)n_in; (void)out_size; (void)ws_size;

  char* ws = (char*)d_ws;
  size_t off = 0;
  auto carve = [&](size_t bytes) -> void* {
    void* p = ws + off;
    off += (bytes + 255) & ~(size_t)255;
    return p;
  };
  _Float16* P0 = (_Float16*)carve((size_t)NN * EMB_P * 2);   // agg (holds [N][32] for l0)
  _Float16* P1 = (_Float16*)carve((size_t)NN * EMB_P * 2);   // raw h2 (pre-BN)
  _Float16* Q  = (_Float16*)carve((size_t)NN * HID_P * 2);   // h1
  float* esum   = (float*)carve((size_t)NN * 4);
  int* counts   = (int*)carve((size_t)NN * 4);
  int* row_ptr  = (int*)carve((size_t)(NN + 1) * 4);
  int* cursor   = (int*)carve((size_t)NN * 4);
  int* csr_src  = (int*)carve((size_t)NE * 4);
  _Float16* w1t0 = (_Float16*)carve((size_t)HID_P * DIN_P * 2);
  _Float16* w1t  = (_Float16*)carve((size_t)4 * HID_P * EMB_P * 2);
  _Float16* w2t  = (_Float16*)carve((size_t)5 * EMB_G * HID_P * 2);
  float* b1p   = (float*)carve((size_t)5 * HID_P * 4);
  float* b2p   = (float*)carve((size_t)5 * EMB_G * 4);
  float* stats = (float*)carve(2 * EMB_G * 4);
  float* scale = (float*)carve(EMB_G * 4);
  float* shift = (float*)carve(EMB_G * 4);
  float* graw  = (float*)carve((size_t)NG * EMB_P * 4);

  hipMemsetAsync(esum, 0, (size_t)NN * 4, stream);
  hipMemsetAsync(counts, 0, (size_t)NN * 4, stream);
  hipMemsetAsync(graw, 0, (size_t)NG * EMB_P * 4, stream);

  // CSR by dst + per-node edge-feature sums
  count_edges_kernel<<<(NE + 255) / 256, 256, 0, stream>>>(dst, edge_feats, counts, esum);
  scan_kernel<<<1, 1024, 0, stream>>>(counts, row_ptr, cursor);
  scatter_kernel<<<(NE + 255) / 256, 256, 0, stream>>>(src, dst, cursor, csr_src);

  // weight repacks (fp16, transposed [Npad][K], zero-padded)
  repack_wt_kernel<<<(HID_P * DIN_P + 255) / 256, 256, 0, stream>>>(w1_0, w1t0, DIN, DHID, HID_P, DIN_P);
  for (int l = 0; l < 4; ++l) {
    repack_wt_kernel<<<(HID_P * EMB_P + 255) / 256, 256, 0, stream>>>(
        w1s + (size_t)l * DEMB * DHID, w1t + (size_t)l * HID_P * EMB_P, DEMB, DHID, HID_P, EMB_P);
  }
  repack_wt_kernel<<<(EMB_G * HID_P + 255) / 256, 256, 0, stream>>>(w2_0, w2t, DHID, DEMB, EMB_G, HID_P);
  for (int l = 0; l < 4; ++l) {
    repack_wt_kernel<<<(EMB_G * HID_P + 255) / 256, 256, 0, stream>>>(
        w2s + (size_t)l * DHID * DEMB, w2t + (size_t)(l + 1) * EMB_G * HID_P, DHID, DEMB, EMB_G, HID_P);
  }
  pad_bias_kernel<<<(HID_P + 255) / 256, 256, 0, stream>>>(b1_0, b1p, DHID, HID_P);
  pad_bias_kernel<<<(EMB_G + 255) / 256, 256, 0, stream>>>(b2_0, b2p, DEMB, EMB_G);
  for (int l = 0; l < 4; ++l) {
    pad_bias_kernel<<<(HID_P + 255) / 256, 256, 0, stream>>>(b1s + (size_t)l * DHID, b1p + (size_t)(l + 1) * HID_P, DHID, HID_P);
    pad_bias_kernel<<<(EMB_G + 255) / 256, 256, 0, stream>>>(b2s + (size_t)l * DEMB, b2p + (size_t)(l + 1) * EMB_G, DEMB, EMB_G);
  }

  const int MT = (NN + 127) / 128;  // 782 M-tiles
  const int spmm_blocks = (NN * 64 + 255) / 256;

  for (int l = 0; l < 5; ++l) {
    const _Float16* w1t_l = (l == 0) ? w1t0 : w1t + (size_t)(l - 1) * HID_P * EMB_P;
    const _Float16* w2t_l = w2t + (size_t)l * EMB_G * HID_P;
    const float* b1p_l = b1p + (size_t)l * HID_P;
    const float* b2p_l = b2p + (size_t)l * EMB_G;
    const float* ga = (l == 0) ? gamma_0 : gammas + (size_t)(l - 1) * DEMB;
    const float* be = (l == 0) ? beta_0 : betas + (size_t)(l - 1) * DEMB;
    int K1 = (l == 0) ? DIN_P : EMB_P;

    if (l == 0) {
      spmm0_kernel<<<spmm_blocks, 256, 0, stream>>>(node_feats, row_ptr, csr_src, esum, P0);
    } else {
      spmm_f16_kernel<<<spmm_blocks, 256, 0, stream>>>(P1, scale, shift, row_ptr, csr_src, esum, P0);
    }

    gemm_rs_kernel<true, false><<<dim3(HID_P / 128, MT), 256, 0, stream>>>(
        P0, w1t_l, b1p_l, Q, NN, K1, HID_P, HID_P, nullptr);

    hipMemsetAsync(stats, 0, 2 * EMB_G * 4, stream);
    gemm_rs_kernel<false, true><<<dim3(EMB_G / 128, MT), 256, 0, stream>>>(
        Q, w2t_l, b2p_l, P1, NN, HID_P, EMB_P, EMB_P, stats);

    bn_finalize_kernel<<<1, EMB_G, 0, stream>>>(stats, ga, be, scale, shift);
  }

  pool2_kernel<<<POOL_BLOCKS, 256, 0, stream>>>(P1, gid, graw);
  final_kernel<<<NG, 64, 0, stream>>>(graw, gid, scale, shift, wt, bt, out);
}

// Round 4
// 2413.938 us; speedup vs baseline: 4.2366x; 1.2706x over previous
//
#include <hip/hip_runtime.h>

#define NN 100000
#define NE 1600000
#define NG 128
#define DIN 20
#define DEMB 300
#define DHID 600
#define DOUT 64
// padded dims
#define DIN_P 32
#define EMB_P 320   // activation storage width (multiple of 32)
#define HID_P 640
#define EMB_G 384   // gemm2 N-dim padding (multiple of 128)
#define SCAN_BLK 392  // ceil(NN/256)

static const float BN_EPS_F = 1e-5f;

typedef _Float16 f16x8 __attribute__((ext_vector_type(8)));
typedef float f32x4 __attribute__((ext_vector_type(4)));

// async global->LDS, 16B per lane; LDS dst = wave-uniform base + lane*16
__device__ __forceinline__ void gload_lds16(const void* g, const void* l) {
  __builtin_amdgcn_global_load_lds(
      (const __attribute__((address_space(1))) unsigned int*)(unsigned long long)g,
      (__attribute__((address_space(3))) unsigned int*)(unsigned long long)(unsigned int)(unsigned long long)l,
      16, 0, 0);
}

// ---------------- CSR build (once per call) ----------------

__global__ void count_edges_kernel(const int* __restrict__ dst, const float* __restrict__ ef,
                                   int* __restrict__ counts, float* __restrict__ esum) {
  int e = blockIdx.x * blockDim.x + threadIdx.x;
  if (e >= NE) return;
  int v = dst[e];
  atomicAdd(&counts[v], 1);
  atomicAdd(&esum[v], ef[e]);
}

// 3-phase exclusive scan of counts -> row_ptr/cursor
__global__ __launch_bounds__(256) void scan_part1(const int* __restrict__ counts,
                                                  int* __restrict__ bsums) {
  __shared__ int red[256];
  int t = threadIdx.x;
  int i = blockIdx.x * 256 + t;
  red[t] = (i < NN) ? counts[i] : 0;
  __syncthreads();
  for (int s = 128; s > 0; s >>= 1) {
    if (t < s) red[t] += red[t + s];
    __syncthreads();
  }
  if (t == 0) bsums[blockIdx.x] = red[0];
}

__global__ __launch_bounds__(512) void scan_part2(const int* __restrict__ bsums,
                                                  int* __restrict__ boffs) {
  __shared__ int sc[512];
  int t = threadIdx.x;
  int v = (t < SCAN_BLK) ? bsums[t] : 0;
  sc[t] = v;
  __syncthreads();
  for (int off = 1; off < 512; off <<= 1) {
    int u = (t >= off) ? sc[t - off] : 0;
    __syncthreads();
    sc[t] += u;
    __syncthreads();
  }
  if (t < SCAN_BLK) boffs[t] = sc[t] - v;  // exclusive
}

__global__ __launch_bounds__(256) void scan_part3(const int* __restrict__ counts,
                                                  const int* __restrict__ boffs,
                                                  int* __restrict__ row_ptr,
                                                  int* __restrict__ cursor) {
  __shared__ int sc[256];
  int t = threadIdx.x;
  int i = blockIdx.x * 256 + t;
  int v = (i < NN) ? counts[i] : 0;
  sc[t] = v;
  __syncthreads();
  for (int off = 1; off < 256; off <<= 1) {
    int u = (t >= off) ? sc[t - off] : 0;
    __syncthreads();
    sc[t] += u;
    __syncthreads();
  }
  if (i < NN) {
    int excl = sc[t] - v + boffs[blockIdx.x];
    row_ptr[i] = excl;
    cursor[i] = excl;
  }
  if (i == NN - 1) row_ptr[NN] = NE;
}

__global__ void scatter_kernel(const int* __restrict__ src, const int* __restrict__ dst,
                               int* __restrict__ cursor, int* __restrict__ csr_src) {
  int e = blockIdx.x * blockDim.x + threadIdx.x;
  if (e >= NE) return;
  int pos = atomicAdd(&cursor[dst[e]], 1);
  csr_src[pos] = src[e];
}

// ---------------- weight repack: w[K][Nsrc] fp32 -> wt[Np][Kp] fp16 (transposed, zero-pad) ----

__global__ void repack_wt_kernel(const float* __restrict__ w, _Float16* __restrict__ out,
                                 int K, int Nsrc, int Np, int Kp) {
  int idx = blockIdx.x * blockDim.x + threadIdx.x;
  if (idx >= Np * Kp) return;
  int n = idx / Kp, k = idx - n * Kp;
  float v = (n < Nsrc && k < K) ? w[(size_t)k * Nsrc + n] : 0.f;
  out[idx] = (_Float16)v;
}

__global__ void pad_bias_kernel(const float* __restrict__ b, float* __restrict__ out, int n, int np) {
  int i = blockIdx.x * blockDim.x + threadIdx.x;
  if (i >= np) return;
  out[i] = (i < n) ? b[i] : 0.f;
}

// ---------------- layer-0 spmm: fp32 x[N][20] -> fp16 agg0[N][32] ----------------

__global__ __launch_bounds__(256) void spmm0_kernel(const float* __restrict__ x,
                                                    const int* __restrict__ row_ptr,
                                                    const int* __restrict__ csr_src,
                                                    const float* __restrict__ esum,
                                                    _Float16* __restrict__ out) {
  int wid = (blockIdx.x * blockDim.x + threadIdx.x) >> 6;
  int lane = threadIdx.x & 63;
  if (wid >= NN) return;
  int beg = row_ptr[wid], end = row_ptr[wid + 1];
  float acc = 0.f;
  int j = beg;
  for (; j + 1 < end; j += 2) {
    int s0 = csr_src[j], s1 = csr_src[j + 1];
    if (lane < DIN) {
      acc += x[(size_t)s0 * DIN + lane];
      acc += x[(size_t)s1 * DIN + lane];
    }
  }
  if (j < end) {
    int s0 = csr_src[j];
    if (lane < DIN) acc += x[(size_t)s0 * DIN + lane];
  }
  if (lane < DIN_P) {
    float v = (lane < DIN) ? acc + esum[wid] : 0.f;
    out[(size_t)wid * DIN_P + lane] = (_Float16)v;
  }
}

// ---------------- fused spmm (layers 1..4): gather raw h2 fp16, apply prev BN on the fly ----

__global__ __launch_bounds__(256) void spmm_f16_kernel(const _Float16* __restrict__ x,
                                                       const float* __restrict__ scale,
                                                       const float* __restrict__ shift,
                                                       const int* __restrict__ row_ptr,
                                                       const int* __restrict__ csr_src,
                                                       const float* __restrict__ esum,
                                                       _Float16* __restrict__ out) {
  int wid = (blockIdx.x * blockDim.x + threadIdx.x) >> 6;
  int lane = threadIdx.x & 63;
  if (wid >= NN) return;
  int beg = row_ptr[wid], end = row_ptr[wid + 1];
  float deg = (float)(end - beg);
  float es = esum[wid];
  if (lane >= 40) return;
  const f16x8* xb = (const f16x8*)x;
  float acc[8] = {};
  int j = beg;
  for (; j + 7 < end; j += 8) {
    int s0 = csr_src[j + 0], s1 = csr_src[j + 1], s2 = csr_src[j + 2], s3 = csr_src[j + 3];
    int s4 = csr_src[j + 4], s5 = csr_src[j + 5], s6 = csr_src[j + 6], s7 = csr_src[j + 7];
    f16x8 v0 = xb[(size_t)s0 * 40 + lane];
    f16x8 v1 = xb[(size_t)s1 * 40 + lane];
    f16x8 v2 = xb[(size_t)s2 * 40 + lane];
    f16x8 v3 = xb[(size_t)s3 * 40 + lane];
    f16x8 v4 = xb[(size_t)s4 * 40 + lane];
    f16x8 v5 = xb[(size_t)s5 * 40 + lane];
    f16x8 v6 = xb[(size_t)s6 * 40 + lane];
    f16x8 v7 = xb[(size_t)s7 * 40 + lane];
#pragma unroll
    for (int i = 0; i < 8; ++i) {
      acc[i] += ((float)v0[i] + (float)v1[i]) + ((float)v2[i] + (float)v3[i]) +
                ((float)v4[i] + (float)v5[i]) + ((float)v6[i] + (float)v7[i]);
    }
  }
  for (; j < end; ++j) {
    f16x8 v0 = xb[(size_t)csr_src[j] * 40 + lane];
#pragma unroll
    for (int i = 0; i < 8; ++i) acc[i] += (float)v0[i];
  }
  int c = lane * 8;
  f16x8 o;
#pragma unroll
  for (int i = 0; i < 8; ++i)
    o[i] = (_Float16)(acc[i] * scale[c + i] + deg * shift[c + i] + es);
  ((f16x8*)(out))[(size_t)wid * 40 + lane] = o;
}

// ---------------- m97-style MFMA GEMM: C[M][ldC] = A[M][K] @ Bt[Npad][K]^T + bias ----
// 256 threads = 4 waves (2x2); block tile 128x128; BK=32; 16 KB LDS staged via
// global_load_lds (16B/lane) in exact MFMA fragment order. Optional fused BN stats.

template <bool RELU, bool STATS>
__global__ __launch_bounds__(256) void gemm_lds_kernel(const _Float16* __restrict__ A,
                                                       const _Float16* __restrict__ Bt,
                                                       const float* __restrict__ bias,
                                                       _Float16* __restrict__ C,
                                                       int M, int K, int ldC, int NREAL,
                                                       float* __restrict__ stats) {
  __shared__ _Float16 lds[16 * 512];  // 8 A-chunks + 8 B-chunks, 1 KB each
  const int t = threadIdx.x;
  const int wv = t >> 6;
  const int lane = t & 63;
  const int fm = lane & 15;
  const int k8 = (lane >> 4) * 8;
  const int m0 = blockIdx.y * 128;
  const int n0 = blockIdx.x * 128;
  const int wmq = (wv >> 1) * 4;  // this wave's A-chunk base (x16 rows)
  const int wnq = (wv & 1) * 4;   // this wave's B-chunk base (x16 cols)

  // staging pointers: wave wv stages A-chunks {2wv,2wv+1} and B-chunks {2wv,2wv+1}
  const _Float16* ApS[2];
  const _Float16* BpS[2];
#pragma unroll
  for (int i = 0; i < 2; ++i) {
    int mi = 2 * wv + i;
    int r = min(m0 + mi * 16 + fm, M - 1);
    ApS[i] = A + (size_t)r * K + k8;
    BpS[i] = Bt + (size_t)(n0 + mi * 16 + fm) * K + k8;
  }

  f32x4 acc[4][4] = {};

  for (int k0 = 0; k0 < K; k0 += 32) {
#pragma unroll
    for (int i = 0; i < 2; ++i) {
      int mi = 2 * wv + i;
      gload_lds16(ApS[i] + k0, &lds[mi * 512 + lane * 8]);
      gload_lds16(BpS[i] + k0, &lds[(8 + mi) * 512 + lane * 8]);
    }
    __syncthreads();
    f16x8 a[4], b[4];
#pragma unroll
    for (int i = 0; i < 4; ++i) a[i] = *(const f16x8*)&lds[(wmq + i) * 512 + lane * 8];
#pragma unroll
    for (int i = 0; i < 4; ++i) b[i] = *(const f16x8*)&lds[(8 + wnq + i) * 512 + lane * 8];
#pragma unroll
    for (int mi = 0; mi < 4; ++mi)
#pragma unroll
      for (int ni = 0; ni < 4; ++ni)
        acc[mi][ni] = __builtin_amdgcn_mfma_f32_16x16x32_f16(a[mi], b[ni], acc[mi][ni], 0, 0, 0);
    __syncthreads();
  }

  // epilogue: C/D layout col=lane&15, row=(lane>>4)*4+reg
  float bi[4];
#pragma unroll
  for (int ni = 0; ni < 4; ++ni) bi[ni] = bias[n0 + (wnq + ni) * 16 + fm];
  const int rq = (lane >> 4) * 4;
  float ssum[4] = {}, ssq[4] = {};
#pragma unroll
  for (int mi = 0; mi < 4; ++mi) {
#pragma unroll
    for (int ni = 0; ni < 4; ++ni) {
      int col = n0 + (wnq + ni) * 16 + fm;
#pragma unroll
      for (int r = 0; r < 4; ++r) {
        int row = m0 + (wmq + mi) * 16 + rq + r;
        float v = acc[mi][ni][r] + bi[ni];
        if (RELU) v = fmaxf(v, 0.f);
        if (row < M && col < NREAL) C[(size_t)row * ldC + col] = (_Float16)v;
        if (STATS && row < M) { ssum[ni] += v; ssq[ni] += v * v; }
      }
    }
  }
  if (STATS) {
    float* sred = (float*)lds;  // reuse LDS: 2 x 128 floats
    if (t < 128) { sred[t] = 0.f; sred[128 + t] = 0.f; }
    __syncthreads();
    const int wn = (wv & 1) * 64;
#pragma unroll
    for (int ni = 0; ni < 4; ++ni) {
      atomicAdd(&sred[wn + ni * 16 + fm], ssum[ni]);
      atomicAdd(&sred[128 + wn + ni * 16 + fm], ssq[ni]);
    }
    __syncthreads();
    if (t < 128) {
      int gc = blockIdx.x * 128 + t;
      atomicAdd(&stats[gc], sred[t]);
      atomicAdd(&stats[EMB_G + gc], sred[128 + t]);
    }
  }
}

// ---------------- BN finalize ----------------

__global__ void bn_finalize_kernel(const float* __restrict__ stats, const float* __restrict__ gamma,
                                   const float* __restrict__ beta, float* __restrict__ scale,
                                   float* __restrict__ shift) {
  int c = threadIdx.x;
  if (c >= EMB_G) return;
  if (c < DEMB) {
    float mu = stats[c] / (float)NN;
    float var = fmaxf(stats[EMB_G + c] / (float)NN - mu * mu, 0.f);
    float sc = gamma[c] * rsqrtf(var + BN_EPS_F);
    scale[c] = sc;
    shift[c] = beta[c] - mu * sc;
  } else {
    scale[c] = 0.f;
    shift[c] = 0.f;
  }
}

// ---------------- readout ----------------

#define POOL_BLOCKS 784

__global__ __launch_bounds__(256) void pool2_kernel(const _Float16* __restrict__ h,
                                                    const int* __restrict__ gid,
                                                    float* __restrict__ graw) {
  const int w = (blockIdx.x * 256 + threadIdx.x) >> 6;
  const int lane = threadIdx.x & 63;
  const int NW = POOL_BLOCKS * 4;
  const int rpw = (NN + NW - 1) / NW;
  int r0 = w * rpw, r1 = min(r0 + rpw, NN);
  if (r0 >= r1 || lane >= 40) return;
  const f16x8* hb = (const f16x8*)h;
  float acc[8] = {};
  int curg = gid[r0];
  for (int r = r0; r < r1; ++r) {
    int g = gid[r];
    if (g != curg) {
#pragma unroll
      for (int i = 0; i < 8; ++i) {
        atomicAdd(&graw[curg * EMB_P + lane * 8 + i], acc[i]);
        acc[i] = 0.f;
      }
      curg = g;
    }
    f16x8 v = hb[(size_t)r * 40 + lane];
#pragma unroll
    for (int i = 0; i < 8; ++i) acc[i] += (float)v[i];
  }
#pragma unroll
  for (int i = 0; i < 8; ++i) atomicAdd(&graw[curg * EMB_P + lane * 8 + i], acc[i]);
}

__global__ void final_kernel(const float* __restrict__ graw, const int* __restrict__ gid,
                             const float* __restrict__ scale, const float* __restrict__ shift,
                             const float* __restrict__ wt, const float* __restrict__ bt,
                             float* __restrict__ out) {
  int g = blockIdx.x, t = threadIdx.x;  // 64 threads
  __shared__ int sb[2];
  if (t < 2) {
    int target = g + t;
    int lo = 0, hi = NN;
    while (lo < hi) {
      int m = (lo + hi) >> 1;
      if (gid[m] < target) lo = m + 1; else hi = m;
    }
    sb[t] = lo;
  }
  __syncthreads();
  int cnt = sb[1] - sb[0];
  float inv = cnt > 0 ? 1.0f / (float)cnt : 0.f;
  float sh_on = cnt > 0 ? 1.0f : 0.f;
  float acc = bt[t];
  const float* row = graw + g * EMB_P;
  for (int k = 0; k < DEMB; ++k) {
    float gf = row[k] * inv * scale[k] + sh_on * shift[k];
    acc = fmaf(gf, wt[k * DOUT + t], acc);
  }
  out[g * DOUT + t] = acc;
}

// ---------------- launch ----------------

extern "C" void kernel_launch(void* const* d_in, const int* in_sizes, int n_in,
                              void* d_out, int out_size, void* d_ws, size_t ws_size,
                              hipStream_t stream) {
  const float* node_feats = (const float*)d_in[0];
  const float* edge_feats = (const float*)d_in[1];
  const int* src = (const int*)d_in[2];
  const int* dst = (const int*)d_in[3];
  const int* gid = (const int*)d_in[4];
  const float* w1_0 = (const float*)d_in[5];
  const float* b1_0 = (const float*)d_in[6];
  const float* w2_0 = (const float*)d_in[7];
  const float* b2_0 = (const float*)d_in[8];
  const float* gamma_0 = (const float*)d_in[9];
  const float* beta_0 = (const float*)d_in[10];
  const float* w1s = (const float*)d_in[11];
  const float* b1s = (const float*)d_in[12];
  const float* w2s = (const float*)d_in[13];
  const float* b2s = (const float*)d_in[14];
  const float* gammas = (const float*)d_in[15];
  const float* betas = (const float*)d_in[16];
  const float* wt = (const float*)d_in[17];
  const float* bt = (const float*)d_in[18];
  float* out = (float*)d_out;
  (void)in_sizes; (void)n_in; (void)out_size; (void)ws_size;

  char* ws = (char*)d_ws;
  size_t off = 0;
  auto carve = [&](size_t bytes) -> void* {
    void* p = ws + off;
    off += (bytes + 255) & ~(size_t)255;
    return p;
  };
  _Float16* P0 = (_Float16*)carve((size_t)NN * EMB_P * 2);   // agg (holds [N][32] for l0)
  _Float16* P1 = (_Float16*)carve((size_t)NN * EMB_P * 2);   // raw h2 (pre-BN)
  _Float16* Q  = (_Float16*)carve((size_t)NN * HID_P * 2);   // h1
  float* esum   = (float*)carve((size_t)NN * 4);
  int* counts   = (int*)carve((size_t)NN * 4);
  int* row_ptr  = (int*)carve((size_t)(NN + 1) * 4);
  int* cursor   = (int*)carve((size_t)NN * 4);
  int* csr_src  = (int*)carve((size_t)NE * 4);
  int* bsums    = (int*)carve((size_t)SCAN_BLK * 4);
  int* boffs    = (int*)carve((size_t)SCAN_BLK * 4);
  _Float16* w1t0 = (_Float16*)carve((size_t)HID_P * DIN_P * 2);
  _Float16* w1t  = (_Float16*)carve((size_t)4 * HID_P * EMB_P * 2);
  _Float16* w2t  = (_Float16*)carve((size_t)5 * EMB_G * HID_P * 2);
  float* b1p   = (float*)carve((size_t)5 * HID_P * 4);
  float* b2p   = (float*)carve((size_t)5 * EMB_G * 4);
  float* stats = (float*)carve(2 * EMB_G * 4);
  float* scale = (float*)carve(EMB_G * 4);
  float* shift = (float*)carve(EMB_G * 4);
  float* graw  = (float*)carve((size_t)NG * EMB_P * 4);

  hipMemsetAsync(esum, 0, (size_t)NN * 4, stream);
  hipMemsetAsync(counts, 0, (size_t)NN * 4, stream);
  hipMemsetAsync(graw, 0, (size_t)NG * EMB_P * 4, stream);

  // CSR by dst + per-node edge-feature sums
  count_edges_kernel<<<(NE + 255) / 256, 256, 0, stream>>>(dst, edge_feats, counts, esum);
  scan_part1<<<SCAN_BLK, 256, 0, stream>>>(counts, bsums);
  scan_part2<<<1, 512, 0, stream>>>(bsums, boffs);
  scan_part3<<<SCAN_BLK, 256, 0, stream>>>(counts, boffs, row_ptr, cursor);
  scatter_kernel<<<(NE + 255) / 256, 256, 0, stream>>>(src, dst, cursor, csr_src);

  // weight repacks (fp16, transposed [Npad][K], zero-padded)
  repack_wt_kernel<<<(HID_P * DIN_P + 255) / 256, 256, 0, stream>>>(w1_0, w1t0, DIN, DHID, HID_P, DIN_P);
  for (int l = 0; l < 4; ++l) {
    repack_wt_kernel<<<(HID_P * EMB_P + 255) / 256, 256, 0, stream>>>(
        w1s + (size_t)l * DEMB * DHID, w1t + (size_t)l * HID_P * EMB_P, DEMB, DHID, HID_P, EMB_P);
  }
  repack_wt_kernel<<<(EMB_G * HID_P + 255) / 256, 256, 0, stream>>>(w2_0, w2t, DHID, DEMB, EMB_G, HID_P);
  for (int l = 0; l < 4; ++l) {
    repack_wt_kernel<<<(EMB_G * HID_P + 255) / 256, 256, 0, stream>>>(
        w2s + (size_t)l * DHID * DEMB, w2t + (size_t)(l + 1) * EMB_G * HID_P, DHID, DEMB, EMB_G, HID_P);
  }
  pad_bias_kernel<<<(HID_P + 255) / 256, 256, 0, stream>>>(b1_0, b1p, DHID, HID_P);
  pad_bias_kernel<<<(EMB_G + 255) / 256, 256, 0, stream>>>(b2_0, b2p, DEMB, EMB_G);
  for (int l = 0; l < 4; ++l) {
    pad_bias_kernel<<<(HID_P + 255) / 256, 256, 0, stream>>>(b1s + (size_t)l * DHID, b1p + (size_t)(l + 1) * HID_P, DHID, HID_P);
    pad_bias_kernel<<<(EMB_G + 255) / 256, 256, 0, stream>>>(b2s + (size_t)l * DEMB, b2p + (size_t)(l + 1) * EMB_G, DEMB, EMB_G);
  }

  const int MT = (NN + 127) / 128;  // 782 M-tiles
  const int spmm_blocks = (NN * 64 + 255) / 256;

  for (int l = 0; l < 5; ++l) {
    const _Float16* w1t_l = (l == 0) ? w1t0 : w1t + (size_t)(l - 1) * HID_P * EMB_P;
    const _Float16* w2t_l = w2t + (size_t)l * EMB_G * HID_P;
    const float* b1p_l = b1p + (size_t)l * HID_P;
    const float* b2p_l = b2p + (size_t)l * EMB_G;
    const float* ga = (l == 0) ? gamma_0 : gammas + (size_t)(l - 1) * DEMB;
    const float* be = (l == 0) ? beta_0 : betas + (size_t)(l - 1) * DEMB;
    int K1 = (l == 0) ? DIN_P : EMB_P;

    if (l == 0) {
      spmm0_kernel<<<spmm_blocks, 256, 0, stream>>>(node_feats, row_ptr, csr_src, esum, P0);
    } else {
      spmm_f16_kernel<<<spmm_blocks, 256, 0, stream>>>(P1, scale, shift, row_ptr, csr_src, esum, P0);
    }

    gemm_lds_kernel<true, false><<<dim3(HID_P / 128, MT), 256, 0, stream>>>(
        P0, w1t_l, b1p_l, Q, NN, K1, HID_P, HID_P, nullptr);

    hipMemsetAsync(stats, 0, 2 * EMB_G * 4, stream);
    gemm_lds_kernel<false, true><<<dim3(EMB_G / 128, MT), 256, 0, stream>>>(
        Q, w2t_l, b2p_l, P1, NN, HID_P, EMB_P, EMB_P, stats);

    bn_finalize_kernel<<<1, EMB_G, 0, stream>>>(stats, ga, be, scale, shift);
  }

  pool2_kernel<<<POOL_BLOCKS, 256, 0, stream>>>(P1, gid, graw);
  final_kernel<<<NG, 64, 0, stream>>>(graw, gid, scale, shift, wt, bt, out);
}